// Round 2
// baseline (72.996 us; speedup 1.0000x reference)
//
#include <hip/hip_runtime.h>

// SparseLookupTable: out[b,o] = sum_{k<128} lut[inp[b,k], wgt[o,k]]
// B=512, O=1024, K=128, LUT 256x256 fp32.
//
// R2 strategy: fp16 LUT resident in LDS (128 KB). Tile = 16 b-rows x 128
// o-cols per 1024-thread block; wave = one b-row (row index wave-uniform ->
// readfirstlane -> SALU row offsets), lane = o (gather banks fully random,
// ~conflict-free). 2 outputs/thread, dual accumulators to break add chains.

#define BATCH 512
#define OUTF  1024
#define KDIM  128
#define MIDX  256

typedef _Float16 half4v __attribute__((ext_vector_type(4)));

__global__ __launch_bounds__(1024, 1)
void slt_kernel(const int* __restrict__ inp, const int* __restrict__ wgt,
                const float* __restrict__ lut, float* __restrict__ out) {
    // 128 KB LUT + 2 KB row-index bytes + 16 KB col-index bytes = 146 KB LDS
    __shared__ __attribute__((aligned(16))) _Float16 lut16[MIDX * MIDX];
    __shared__ __attribute__((aligned(16))) unsigned int wrow_pack[16 * 32];   // [b][q] packed 4x u8
    __shared__ __attribute__((aligned(16))) unsigned int wcol_pack[32 * 128];  // [q][o] packed 4x u8

    const int tid   = threadIdx.x;
    const int otile = blockIdx.x;   // 8 tiles of 128 outputs
    const int btile = blockIdx.y;   // 32 tiles of 16 batch rows

    // ---- stage LUT fp32 -> fp16 (each thread: 16 x float4 -> half4) ----
    const float4* lut4 = (const float4*)lut;
    half4v* l16v = (half4v*)lut16;
    #pragma unroll
    for (int it = 0; it < 16; ++it) {
        int idx = it * 1024 + tid;
        float4 v = lut4[idx];
        half4v h = { (_Float16)v.x, (_Float16)v.y, (_Float16)v.z, (_Float16)v.w };
        l16v[idx] = h;
    }

    // ---- stage input rows, u8-packed: wrow_pack[b*32+q] = inp[b][4q..4q+3] ----
    if (tid < 512) {
        int b = tid >> 5;
        int q = tid & 31;
        const int4 iv = *(const int4*)(inp + ((size_t)(btile * 16 + b)) * KDIM + q * 4);
        wrow_pack[b * 32 + q] = (unsigned int)(iv.x & 255)
                              | ((unsigned int)(iv.y & 255) << 8)
                              | ((unsigned int)(iv.z & 255) << 16)
                              | ((unsigned int)(iv.w & 255) << 24);
    }

    // ---- stage weight cols, u8-packed: wcol_pack[q*128+o] = wgt[o][4q..4q+3] ----
    {
        int o = tid >> 3;          // 0..127
        int j = tid & 7;
        const int* wbase = wgt + ((size_t)(otile * 128 + o)) * KDIM;
        #pragma unroll
        for (int i = 0; i < 4; ++i) {
            int q = j + 8 * i;     // coalesced: consecutive j -> consecutive int4
            const int4 wv = *(const int4*)(wbase + q * 4);
            wcol_pack[q * 128 + o] = (unsigned int)(wv.x & 255)
                                   | ((unsigned int)(wv.y & 255) << 8)
                                   | ((unsigned int)(wv.z & 255) << 16)
                                   | ((unsigned int)(wv.w & 255) << 24);
        }
    }

    __syncthreads();

    const int w    = tid >> 6;  // wave id -> b-row within tile
    const int lane = tid & 63;  // o; handles o=lane and o=lane+64

    float a0 = 0.f, a1 = 0.f, b0 = 0.f, b1 = 0.f;
    const unsigned int* wr = &wrow_pack[w * 32];

    #pragma unroll 4
    for (int q = 0; q < 32; ++q) {
        // wave-uniform row word -> SGPR; row offsets become SALU
        unsigned int rword = __builtin_amdgcn_readfirstlane(wr[q]);
        unsigned int w0 = wcol_pack[q * 128 + lane];
        unsigned int w1 = wcol_pack[q * 128 + lane + 64];

        const _Float16* r0 = lut16 + (((rword      ) & 255u) << 8);
        const _Float16* r1 = lut16 + (((rword >>  8) & 255u) << 8);
        const _Float16* r2 = lut16 + (((rword >> 16) & 255u) << 8);
        const _Float16* r3 = lut16 + (((rword >> 24)       ) << 8);

        a0 += (float)r0[(w0      ) & 255u];  a1 += (float)r0[(w1      ) & 255u];
        b0 += (float)r1[(w0 >>  8) & 255u];  b1 += (float)r1[(w1 >>  8) & 255u];
        a0 += (float)r2[(w0 >> 16) & 255u];  a1 += (float)r2[(w1 >> 16) & 255u];
        b0 += (float)r3[(w0 >> 24)        ];  b1 += (float)r3[(w1 >> 24)        ];
    }

    size_t ob = ((size_t)(btile * 16 + w)) * OUTF + (size_t)(otile * 128) + lane;
    out[ob]      = a0 + b0;
    out[ob + 64] = a1 + b1;
}

extern "C" void kernel_launch(void* const* d_in, const int* in_sizes, int n_in,
                              void* d_out, int out_size, void* d_ws, size_t ws_size,
                              hipStream_t stream) {
    const int*   inp = (const int*)d_in[0];    // (512, 32, 4) int32
    const int*   wgt = (const int*)d_in[1];    // (1024, 32, 4) int32
    const float* lut = (const float*)d_in[2];  // (256, 256) fp32
    float*       out = (float*)d_out;          // (512, 1024) fp32

    dim3 grid(8, 32);   // otiles x btiles = 256 blocks, 1 per CU
    dim3 block(1024);
    slt_kernel<<<grid, block, 0, stream>>>(inp, wgt, lut, out);
}